// Round 4
// baseline (212.949 us; speedup 1.0000x reference)
//
#include <hip/hip_runtime.h>

// NavierStokesLossMAC: B=8, H=W=1024
//   d_in[0] v_old (B,2,H,W) f32 | d_in[1] v_new (B,2,H,W) f32
//   d_in[2] p_new (B,1,H,W) f32 | d_in[3] mask  (B,1,H,W) i32
// out: (B,) f32
//
// R12: per-CU L1-fill-bandwidth model. Every round R8-R11 ran at ~19 GB/s
// of L1-fill traffic per CU (~76% of the copy-ubench 24.6 GB/s/CU) while
// HBM bytes, VMEM instr count, in-flight depth and occupancy all varied ->
// the binding resource is bytes through the CU fill path. Only lever left:
// fewer bytes. RPB 2->4 cuts v-halo from 2.0x to 1.5x (352->270 MB total).
//  * one-shot block, 33 vector loads (24 v + 5 p + 4 mask), no barrier in
//    the load path, compiler free to interleave compute by first-use.
//  * block-internal seams via LDS exchange (no seam VMEM).
//  * XCD-bijective swizzle kept (R11: FETCH 141->98 MB).
//  * tail chunk (y0=1021) handled by row-clamped loads + row-validity
//    folded into the mask (rows 1023/1024 contribute 0).

#define NS_H 1024
#define NS_W 1024
#define RPB 4
#define NBY 256                       // chunks per batch; last does 2 real rows
#define PARTS_PER_B NBY

__device__ __forceinline__ float4 ld4(const float* p) { return *(const float4*)p; }
__device__ __forceinline__ int4  ld4i(const int* p)   { return *(const int4*)p; }
__device__ __forceinline__ float4 avg4(float4 a, float4 b) {
    return make_float4(0.5f*(a.x+b.x), 0.5f*(a.y+b.y), 0.5f*(a.z+b.z), 0.5f*(a.w+b.w));
}
__device__ __forceinline__ float4 sub4(float4 a, float4 b) {
    return make_float4(a.x-b.x, a.y-b.y, a.z-b.z, a.w-b.w);
}

__global__ __launch_bounds__(256, 3) void ns_loss_partial(
    const float* __restrict__ v_old,
    const float* __restrict__ v_new,
    const float* __restrict__ p,
    const int*   __restrict__ mask,
    float* __restrict__ ws)
{
    // XCD-bijective swizzle (2048 % 8 == 0)
    const int blkp = blockIdx.x;
    const int lg   = (blkp & 7) * (NBY) + (blkp >> 3) % NBY + ((blkp >> 3) / NBY) * 0; // see below
    // simpler: logical id = (blk&7)*256 + blk>>3  over 2048 blocks
    const int lg2  = (blkp & 7) * 256 + (blkp >> 3);
    const int b    = lg2 / NBY;
    const int cy   = lg2 % NBY;
    const int y0   = 1 + cy * RPB;          // output rows y0..y0+3 (validity-masked)

    const size_t hw = (size_t)NS_H * NS_W;
    const float* uo = v_old + (size_t)b * 2 * hw;
    const float* wo = uo + hw;
    const float* un = v_new + (size_t)b * 2 * hw;
    const float* wn = un + hw;
    const float* pb = p    + (size_t)b * hw;
    const int*   mb = mask + (size_t)b * hw;

    const int tid  = (int)threadIdx.x;
    const int lane = tid & 63;
    const int wid  = tid >> 6;
    const int x0   = tid * 4;
    const bool has_r = (x0 + 4 < NS_W);     // false only for tid==255 (feeds masked x=1023)

    // window rows R[0..5] = y0-1 .. y0+4, clamped to 1023 (only tail chunk clamps)
    int R1 = y0,     R2 = y0 + 1, R3 = y0 + 2, R4 = y0 + 3, R5 = y0 + 4;
    if (R3 > 1023) R3 = 1023;
    if (R4 > 1023) R4 = 1023;
    if (R5 > 1023) R5 = 1023;
    const int o0 = (y0 - 1) * NS_W + x0;
    const int o1 = R1 * NS_W + x0;
    const int o2 = R2 * NS_W + x0;
    const int o3 = R3 * NS_W + x0;
    const int o4 = R4 * NS_W + x0;
    const int o5 = R5 * NS_W + x0;

    // ---- 33 vector loads ----
    float4 un0 = ld4(un + o0), uo0 = ld4(uo + o0);
    float4 un1 = ld4(un + o1), uo1 = ld4(uo + o1);
    float4 un2 = ld4(un + o2), uo2 = ld4(uo + o2);
    float4 un3 = ld4(un + o3), uo3 = ld4(uo + o3);
    float4 un4 = ld4(un + o4), uo4 = ld4(uo + o4);
    float4 un5 = ld4(un + o5), uo5 = ld4(uo + o5);
    float4 wn0 = ld4(wn + o0), wo0 = ld4(wo + o0);
    float4 wn1 = ld4(wn + o1), wo1 = ld4(wo + o1);
    float4 wn2 = ld4(wn + o2), wo2 = ld4(wo + o2);
    float4 wn3 = ld4(wn + o3), wo3 = ld4(wo + o3);
    float4 wn4 = ld4(wn + o4), wo4 = ld4(wo + o4);
    float4 wn5 = ld4(wn + o5), wo5 = ld4(wo + o5);
    float4 P[5];
    P[0] = ld4(pb + o0); P[1] = ld4(pb + o1); P[2] = ld4(pb + o2);
    P[3] = ld4(pb + o3); P[4] = ld4(pb + o4);
    int4 M[4];
    M[0] = ld4i(mb + o1); M[1] = ld4i(mb + o2);
    M[2] = ld4i(mb + o3); M[3] = ld4i(mb + o4);

    // ---- derived fields ----
    float4 U[6], W[6], DU[4], DW[4];
    U[0] = avg4(un0, uo0); W[0] = avg4(wn0, wo0);
    U[1] = avg4(un1, uo1); W[1] = avg4(wn1, wo1); DU[0] = sub4(un1, uo1); DW[0] = sub4(wn1, wo1);
    U[2] = avg4(un2, uo2); W[2] = avg4(wn2, wo2); DU[1] = sub4(un2, uo2); DW[1] = sub4(wn2, wo2);
    U[3] = avg4(un3, uo3); W[3] = avg4(wn3, wo3); DU[2] = sub4(un3, uo3); DW[2] = sub4(wn3, wo3);
    U[4] = avg4(un4, uo4); W[4] = avg4(wn4, wo4); DU[3] = sub4(un4, uo4); DW[3] = sub4(wn4, wo4);
    U[5] = avg4(un5, uo5); W[5] = avg4(wn5, wo5);

    // ---- block-internal seam exchange (rows y0..y0+3) ----
    __shared__ float edge[4][4][5];
    if (lane == 63) {
        #pragma unroll
        for (int k = 0; k < 4; ++k) {
            edge[wid][k][0] = U[k+1].w; edge[wid][k][1] = W[k+1].w; edge[wid][k][2] = P[k+1].w;
        }
    }
    if (lane == 0) {
        #pragma unroll
        for (int k = 0; k < 4; ++k) {
            edge[wid][k][3] = U[k+1].x; edge[wid][k][4] = W[k+1].x;
        }
    }
    __syncthreads();

    float acc = 0.f;

    #pragma unroll
    for (int k = 0; k < 4; ++k) {
        // row y = y0 + k; window center index k+1
        const float rowvalid = (y0 + k <= NS_H - 2) ? 1.f : 0.f;

        float ul = __shfl_up(U[k+1].w, 1), wl = __shfl_up(W[k+1].w, 1), pl = __shfl_up(P[k+1].w, 1);
        if (lane == 0 && wid > 0) {
            ul = edge[wid-1][k][0]; wl = edge[wid-1][k][1]; pl = edge[wid-1][k][2];
        }
        float ur = __shfl_down(U[k+1].x, 1), wr = __shfl_down(W[k+1].x, 1);
        if (lane == 63 && wid < 3) {
            ur = edge[wid+1][k][3]; wr = edge[wid+1][k][4];
        }
        if (!has_r) { ur = 0.f; wr = 0.f; }   // feeds masked x=1023 only

        const float uc[6]  = {ul, U[k+1].x, U[k+1].y, U[k+1].z, U[k+1].w, ur};
        const float wcv[6] = {wl, W[k+1].x, W[k+1].y, W[k+1].z, W[k+1].w, wr};
        const float uym[4] = {U[k].x, U[k].y, U[k].z, U[k].w};
        const float uyp[4] = {U[k+2].x, U[k+2].y, U[k+2].z, U[k+2].w};
        const float wym[4] = {W[k].x, W[k].y, W[k].z, W[k].w};
        const float wyp[4] = {W[k+2].x, W[k+2].y, W[k+2].z, W[k+2].w};
        const float du[4]  = {DU[k].x, DU[k].y, DU[k].z, DU[k].w};
        const float dw[4]  = {DW[k].x, DW[k].y, DW[k].z, DW[k].w};
        const float pcv[5] = {pl, P[k+1].x, P[k+1].y, P[k+1].z, P[k+1].w};
        const float pym[4] = {P[k].x, P[k].y, P[k].z, P[k].w};
        const int   mm[4]  = {M[k].x, M[k].y, M[k].z, M[k].w};

        #pragma unroll
        for (int j = 0; j < 4; ++j) {
            const int x = x0 + j;
            const float m = ((x >= 1 && x <= NS_W - 2) ? (float)mm[j] : 0.f) * rowvalid;
            const float u_cc = uc[j+1],  u_xm = uc[j],  u_xp = uc[j+2];
            const float w_cc = wcv[j+1], w_xm = wcv[j], w_xp = wcv[j+2];

            float res_x =
                dw[j] * 0.25f
              + w_cc * 0.5f * (w_xp - w_xm)
              + 0.5f * ( 0.5f * (u_cc + u_xm) * (w_cc   - wym[j])
                       + 0.5f * (u_cc + u_xp) * (wyp[j] - w_cc  ) )
              + (pcv[j+1] - pcv[j])
              - 0.1f * (w_xm + w_xp + wym[j] + wyp[j] - 4.f * w_cc);

            float res_y =
                du[j] * 0.25f
              + u_cc * 0.5f * (uyp[j] - uym[j])
              + 0.5f * ( 0.5f * (w_cc + wym[j]) * (u_cc - u_xm)
                       + 0.5f * (w_cc + wyp[j]) * (u_xp - u_cc) )
              + (pcv[j+1] - pym[j])
              - 0.1f * (u_xm + u_xp + uym[j] + uyp[j] - 4.f * u_cc);

            acc += m * (res_x * res_x + res_y * res_y);
        }
    }

    // ---- block reduction: wave shuffle -> 16B LDS -> one plain store ----
    #pragma unroll
    for (int off = 32; off > 0; off >>= 1)
        acc += __shfl_down(acc, off);

    __shared__ float smem[4];
    if (lane == 0) smem[wid] = acc;
    __syncthreads();

    if (tid == 0)
        ws[lg2] = smem[0] + smem[1] + smem[2] + smem[3];
}

__global__ __launch_bounds__(256) void ns_loss_reduce(
    const float* __restrict__ ws, float* __restrict__ out)
{
    const int b = blockIdx.x;
    float acc = 0.f;
    for (int i = threadIdx.x; i < PARTS_PER_B; i += 256)
        acc += ws[b * PARTS_PER_B + i];

    #pragma unroll
    for (int off = 32; off > 0; off >>= 1)
        acc += __shfl_down(acc, off);

    __shared__ float smem[4];
    const int lane = threadIdx.x & 63;
    const int wid  = threadIdx.x >> 6;
    if (lane == 0) smem[wid] = acc;
    __syncthreads();

    if (threadIdx.x == 0) {
        const float inv = 1.0f / ((float)(NS_H - 2) * (float)(NS_W - 2));
        out[b] = (smem[0] + smem[1] + smem[2] + smem[3]) * inv;
    }
}

extern "C" void kernel_launch(void* const* d_in, const int* in_sizes, int n_in,
                              void* d_out, int out_size, void* d_ws, size_t ws_size,
                              hipStream_t stream) {
    const float* v_old = (const float*)d_in[0];
    const float* v_new = (const float*)d_in[1];
    const float* p_new = (const float*)d_in[2];
    const int*   msk   = (const int*)d_in[3];
    float* out = (float*)d_out;
    float* ws  = (float*)d_ws;

    const int B = out_size;   // 8

    ns_loss_partial<<<dim3(B * NBY), dim3(256), 0, stream>>>(v_old, v_new, p_new, msk, ws);
    ns_loss_reduce<<<dim3(B), dim3(256), 0, stream>>>(ws, out);
}

// Round 5
// 200.002 us; speedup vs baseline: 1.0647x; 1.0647x over previous
//
#include <hip/hip_runtime.h>

// NavierStokesLossMAC: B=8, H=W=1024
//   d_in[0] v_old (B,2,H,W) f32 | d_in[1] v_new (B,2,H,W) f32
//   d_in[2] p_new (B,1,H,W) f32 | d_in[3] mask  (B,1,H,W) i32
// out: (B,) f32
//
// R13: L2-fill-bytes model. R8/R11 (best, 73-75us) both ran ~4.8 TB/s of
// L2-fill traffic (352 MB incl. 2.0x v-halo); slower rounds all ran BELOW
// that rate (R9/R10 latency-serialized by barriers/1-deep pipe, R12
// spill-stalled: WRITE_SIZE 16 MB canary). Lever: fewer fill bytes at the
// SAME burst structure. 512-thread blocks = two adjacent R11 row-pairs;
// the halves issue loads for shared middle rows (y+1,y+2) near-
// simultaneously -> second request merges with in-flight line (L1/MSHR),
// not a second fill. v-fill 8 rows -> 6 per block (352 -> ~264 MB total).
// Per-thread code identical to R11 (21 loads, VGPR~60, no spill).
//  * XCD-bijective swizzle kept (2048 blocks, %8==0).
//  * block-internal seams via LDS exchange, within each half only.
//  * tail chunk handled by row-clamped loads + row-validity in the mask.

#define NS_H 1024
#define NS_W 1024
#define RPB 4                         // rows per block (two row-pairs)
#define NBY 256                       // chunks per batch; last does 2 real rows
#define PARTS_PER_B NBY

__device__ __forceinline__ float4 ld4(const float* p) { return *(const float4*)p; }
__device__ __forceinline__ int4  ld4i(const int* p)   { return *(const int4*)p; }
__device__ __forceinline__ float4 avg4(float4 a, float4 b) {
    return make_float4(0.5f*(a.x+b.x), 0.5f*(a.y+b.y), 0.5f*(a.z+b.z), 0.5f*(a.w+b.w));
}
__device__ __forceinline__ float4 sub4(float4 a, float4 b) {
    return make_float4(a.x-b.x, a.y-b.y, a.z-b.z, a.w-b.w);
}

__global__ __launch_bounds__(512, 3) void ns_loss_partial(
    const float* __restrict__ v_old,
    const float* __restrict__ v_new,
    const float* __restrict__ p,
    const int*   __restrict__ mask,
    float* __restrict__ ws)
{
    // XCD-bijective swizzle over 2048 blocks (2048 % 8 == 0)
    const int blkp = blockIdx.x;
    const int lg   = (blkp & 7) * NBY + (blkp >> 3);
    const int b    = lg / NBY;
    const int cy   = lg % NBY;
    const int y0   = 1 + cy * RPB;

    const size_t hw = (size_t)NS_H * NS_W;
    const float* uo = v_old + (size_t)b * 2 * hw;
    const float* wo = uo + hw;
    const float* un = v_new + (size_t)b * 2 * hw;
    const float* wn = un + hw;
    const float* pb = p    + (size_t)b * hw;
    const int*   mb = mask + (size_t)b * hw;

    const int tid  = (int)threadIdx.x;
    const int h    = tid >> 8;            // half-block: 0 -> rows y0,y0+1 ; 1 -> y0+2,y0+3
    const int t    = tid & 255;
    const int lane = tid & 63;
    const int wid  = tid >> 6;            // 0..7 global wave id
    const int wih  = (t >> 6);            // wave-in-half 0..3
    const int x0   = t * 4;
    const bool has_r = (t != 255);        // false only for x0==1020 (feeds masked x=1023)

    const int y = y0 + h * 2;             // this half's first output row

    // row indices, clamped (only the tail chunk clamps); validity folded into mask
    int Rm = y - 1, Rc = y, Rp = y + 1, Rq = y + 2;
    if (Rc > 1023) Rc = 1023;
    if (Rp > 1023) Rp = 1023;
    if (Rq > 1023) Rq = 1023;
    const float rv_c = (y     <= NS_H - 2) ? 1.f : 0.f;
    const float rv_p = (y + 1 <= NS_H - 2) ? 1.f : 0.f;

    const int rm  = Rm * NS_W;
    const int rc  = Rc * NS_W;
    const int rp  = Rp * NS_W;
    const int rpp = Rq * NS_W;

    // ---- pure load cluster: 21 vector loads ----
    float4 un_m = ld4(un + rm  + x0), uo_m = ld4(uo + rm  + x0);
    float4 un_c = ld4(un + rc  + x0), uo_c = ld4(uo + rc  + x0);
    float4 un_p = ld4(un + rp  + x0), uo_p = ld4(uo + rp  + x0);
    float4 un_q = ld4(un + rpp + x0), uo_q = ld4(uo + rpp + x0);
    float4 wn_m = ld4(wn + rm  + x0), wo_m = ld4(wo + rm  + x0);
    float4 wn_c = ld4(wn + rc  + x0), wo_c = ld4(wo + rc  + x0);
    float4 wn_p = ld4(wn + rp  + x0), wo_p = ld4(wo + rp  + x0);
    float4 wn_q = ld4(wn + rpp + x0), wo_q = ld4(wo + rpp + x0);
    float4 p_m4 = ld4(pb + rm + x0);
    float4 p_c4 = ld4(pb + rc + x0);
    float4 p_p4 = ld4(pb + rp + x0);
    int4   m_c4 = ld4i(mb + rc + x0);
    int4   m_p4 = ld4i(mb + rp + x0);
    __builtin_amdgcn_sched_barrier(0);   // all 21 loads issued before any compute

    // ---- time-averaged fields & time diffs ----
    float4 u_m = avg4(un_m, uo_m), u_c = avg4(un_c, uo_c);
    float4 u_p = avg4(un_p, uo_p), u_q = avg4(un_q, uo_q);
    float4 w_m = avg4(wn_m, wo_m), w_c = avg4(wn_c, wo_c);
    float4 w_p = avg4(wn_p, wo_p), w_q = avg4(wn_q, wo_q);
    float4 du_c = sub4(un_c, uo_c), du_p = sub4(un_p, uo_p);
    float4 dw_c = sub4(wn_c, wo_c), dw_p = sub4(wn_p, wo_p);

    // ---- wave-edge exchange through LDS (block-internal seams, per half) ----
    __shared__ float edge[8][10];
    if (lane == 63) {
        edge[wid][0] = u_c.w;  edge[wid][1] = w_c.w;  edge[wid][2] = p_c4.w;
        edge[wid][3] = u_p.w;  edge[wid][4] = w_p.w;  edge[wid][5] = p_p4.w;
    }
    if (lane == 0) {
        edge[wid][6] = u_c.x;  edge[wid][7] = w_c.x;
        edge[wid][8] = u_p.x;  edge[wid][9] = w_p.x;
    }
    __syncthreads();

    float ul_c = __shfl_up(u_c.w, 1),  wl_c = __shfl_up(w_c.w, 1);
    float ul_p = __shfl_up(u_p.w, 1),  wl_p = __shfl_up(w_p.w, 1);
    float pl_c = __shfl_up(p_c4.w, 1), pl_p = __shfl_up(p_p4.w, 1);
    if (lane == 0 && wih > 0) {
        ul_c = edge[wid-1][0]; wl_c = edge[wid-1][1]; pl_c = edge[wid-1][2];
        ul_p = edge[wid-1][3]; wl_p = edge[wid-1][4]; pl_p = edge[wid-1][5];
    }
    float ur_c = __shfl_down(u_c.x, 1), wr_c = __shfl_down(w_c.x, 1);
    float ur_p = __shfl_down(u_p.x, 1), wr_p = __shfl_down(w_p.x, 1);
    if (lane == 63 && wih < 3) {
        ur_c = edge[wid+1][6]; wr_c = edge[wid+1][7];
        ur_p = edge[wid+1][8]; wr_p = edge[wid+1][9];
    }
    if (!has_r) { ur_c = 0.f; wr_c = 0.f; ur_p = 0.f; wr_p = 0.f; }  // feeds masked x=1023

    float acc = 0.f;

    // ---- row yc: y- = row m, y+ = row p ----
    {
        const float uc[6]  = {ul_c, u_c.x, u_c.y, u_c.z, u_c.w, ur_c};
        const float wcv[6] = {wl_c, w_c.x, w_c.y, w_c.z, w_c.w, wr_c};
        const float uym[4] = {u_m.x, u_m.y, u_m.z, u_m.w};
        const float uyp[4] = {u_p.x, u_p.y, u_p.z, u_p.w};
        const float wym[4] = {w_m.x, w_m.y, w_m.z, w_m.w};
        const float wyp[4] = {w_p.x, w_p.y, w_p.z, w_p.w};
        const float du[4]  = {du_c.x, du_c.y, du_c.z, du_c.w};
        const float dw[4]  = {dw_c.x, dw_c.y, dw_c.z, dw_c.w};
        const float pcv[5] = {pl_c, p_c4.x, p_c4.y, p_c4.z, p_c4.w};
        const float pym[4] = {p_m4.x, p_m4.y, p_m4.z, p_m4.w};
        const int   mm[4]  = {m_c4.x, m_c4.y, m_c4.z, m_c4.w};

        #pragma unroll
        for (int j = 0; j < 4; ++j) {
            const int x = x0 + j;
            const float m = ((x >= 1 && x <= NS_W - 2) ? (float)mm[j] : 0.f) * rv_c;
            const float u_cc = uc[j+1],  u_xm = uc[j],  u_xp = uc[j+2];
            const float w_cc = wcv[j+1], w_xm = wcv[j], w_xp = wcv[j+2];

            float res_x =
                dw[j] * 0.25f
              + w_cc * 0.5f * (w_xp - w_xm)
              + 0.5f * ( 0.5f * (u_cc + u_xm) * (w_cc   - wym[j])
                       + 0.5f * (u_cc + u_xp) * (wyp[j] - w_cc  ) )
              + (pcv[j+1] - pcv[j])
              - 0.1f * (w_xm + w_xp + wym[j] + wyp[j] - 4.f * w_cc);

            float res_y =
                du[j] * 0.25f
              + u_cc * 0.5f * (uyp[j] - uym[j])
              + 0.5f * ( 0.5f * (w_cc + wym[j]) * (u_cc - u_xm)
                       + 0.5f * (w_cc + wyp[j]) * (u_xp - u_cc) )
              + (pcv[j+1] - pym[j])
              - 0.1f * (u_xm + u_xp + uym[j] + uyp[j] - 4.f * u_cc);

            acc += m * (res_x * res_x + res_y * res_y);
        }
    }

    // ---- row yp: y- = row c, y+ = row q ----
    {
        const float uc[6]  = {ul_p, u_p.x, u_p.y, u_p.z, u_p.w, ur_p};
        const float wcv[6] = {wl_p, w_p.x, w_p.y, w_p.z, w_p.w, wr_p};
        const float uym[4] = {u_c.x, u_c.y, u_c.z, u_c.w};
        const float uyp[4] = {u_q.x, u_q.y, u_q.z, u_q.w};
        const float wym[4] = {w_c.x, w_c.y, w_c.z, w_c.w};
        const float wyp[4] = {w_q.x, w_q.y, w_q.z, w_q.w};
        const float du[4]  = {du_p.x, du_p.y, du_p.z, du_p.w};
        const float dw[4]  = {dw_p.x, dw_p.y, dw_p.z, dw_p.w};
        const float pcv[5] = {pl_p, p_p4.x, p_p4.y, p_p4.z, p_p4.w};
        const float pym[4] = {p_c4.x, p_c4.y, p_c4.z, p_c4.w};
        const int   mm[4]  = {m_p4.x, m_p4.y, m_p4.z, m_p4.w};

        #pragma unroll
        for (int j = 0; j < 4; ++j) {
            const int x = x0 + j;
            const float m = ((x >= 1 && x <= NS_W - 2) ? (float)mm[j] : 0.f) * rv_p;
            const float u_cc = uc[j+1],  u_xm = uc[j],  u_xp = uc[j+2];
            const float w_cc = wcv[j+1], w_xm = wcv[j], w_xp = wcv[j+2];

            float res_x =
                dw[j] * 0.25f
              + w_cc * 0.5f * (w_xp - w_xm)
              + 0.5f * ( 0.5f * (u_cc + u_xm) * (w_cc   - wym[j])
                       + 0.5f * (u_cc + u_xp) * (wyp[j] - w_cc  ) )
              + (pcv[j+1] - pcv[j])
              - 0.1f * (w_xm + w_xp + wym[j] + wyp[j] - 4.f * w_cc);

            float res_y =
                du[j] * 0.25f
              + u_cc * 0.5f * (uyp[j] - uym[j])
              + 0.5f * ( 0.5f * (w_cc + wym[j]) * (u_cc - u_xm)
                       + 0.5f * (w_cc + wyp[j]) * (u_xp - u_cc) )
              + (pcv[j+1] - pym[j])
              - 0.1f * (u_xm + u_xp + uym[j] + uyp[j] - 4.f * u_cc);

            acc += m * (res_x * res_x + res_y * res_y);
        }
    }

    // ---- block reduction: wave shuffle -> 32B LDS -> one plain store ----
    #pragma unroll
    for (int off = 32; off > 0; off >>= 1)
        acc += __shfl_down(acc, off);

    __shared__ float smem[8];
    if (lane == 0) smem[wid] = acc;
    __syncthreads();

    if (tid == 0)
        ws[lg] = smem[0] + smem[1] + smem[2] + smem[3]
               + smem[4] + smem[5] + smem[6] + smem[7];
}

__global__ __launch_bounds__(256) void ns_loss_reduce(
    const float* __restrict__ ws, float* __restrict__ out)
{
    const int b = blockIdx.x;
    float acc = 0.f;
    for (int i = threadIdx.x; i < PARTS_PER_B; i += 256)
        acc += ws[b * PARTS_PER_B + i];

    #pragma unroll
    for (int off = 32; off > 0; off >>= 1)
        acc += __shfl_down(acc, off);

    __shared__ float smem[4];
    const int lane = threadIdx.x & 63;
    const int wid  = threadIdx.x >> 6;
    if (lane == 0) smem[wid] = acc;
    __syncthreads();

    if (threadIdx.x == 0) {
        const float inv = 1.0f / ((float)(NS_H - 2) * (float)(NS_W - 2));
        out[b] = (smem[0] + smem[1] + smem[2] + smem[3]) * inv;
    }
}

extern "C" void kernel_launch(void* const* d_in, const int* in_sizes, int n_in,
                              void* d_out, int out_size, void* d_ws, size_t ws_size,
                              hipStream_t stream) {
    const float* v_old = (const float*)d_in[0];
    const float* v_new = (const float*)d_in[1];
    const float* p_new = (const float*)d_in[2];
    const int*   msk   = (const int*)d_in[3];
    float* out = (float*)d_out;
    float* ws  = (float*)d_ws;

    const int B = out_size;   // 8

    ns_loss_partial<<<dim3(B * NBY), dim3(512), 0, stream>>>(v_old, v_new, p_new, msk, ws);
    ns_loss_reduce<<<dim3(B), dim3(256), 0, stream>>>(ws, out);
}